// Round 2
// 536.120 us; speedup vs baseline: 1.0034x; 1.0034x over previous
//
#include <hip/hip_runtime.h>
#include <hip/hip_bf16.h>

#define IN_CH 512
#define OUT_CH 512
#define HW 64
#define BATCH 16
#define WEIGHT_GAIN 0.014731391274719739f    // 1/sqrt(512*9)
#define MOD_WEIGHT_GAIN 0.04419417382415922f // 1/sqrt(512)

// padded NHWC xs buffer: [B][66][66][512] bf16
#define PAD_W 66
#define XS_PIX_STRIDE 512

typedef __attribute__((ext_vector_type(8))) short frag8;
typedef __attribute__((ext_vector_type(4))) float f32x4;

// ---------------- style[b][i] = (sum_j w[b][j]*mw[i][j])*g + mb[i] ----------------
__global__ void style_kernel(const float* __restrict__ w, const float* __restrict__ mw,
                             const float* __restrict__ mb, float* __restrict__ style) {
    const int gw = (blockIdx.x * 256 + threadIdx.x) >> 6;  // 0..8191
    const int lane = threadIdx.x & 63;
    const int b = gw >> 9;
    const int i = gw & 511;
    const float4* mwp = (const float4*)(mw + (size_t)i * 512 + lane * 8);
    const float4* wp  = (const float4*)(w + (size_t)b * 512 + lane * 8);
    float4 m0 = mwp[0], m1 = mwp[1];
    float4 w0 = wp[0],  w1 = wp[1];
    float s = m0.x * w0.x + m0.y * w0.y + m0.z * w0.z + m0.w * w0.w
            + m1.x * w1.x + m1.y * w1.y + m1.z * w1.z + m1.w * w1.w;
#pragma unroll
    for (int off = 32; off > 0; off >>= 1) s += __shfl_down(s, off, 64);
    if (lane == 0) style[(size_t)b * 512 + i] = s * MOD_WEIGHT_GAIN + mb[i];
}

// ---------------- wsq[o][i] = G^2 * sum_kk weight^2 ; wbf[kk][o][i] = bf16(weight) ----
__global__ void wprep_kernel(const float* __restrict__ weight, float* __restrict__ wsq,
                             __hip_bfloat16* __restrict__ wbf) {
    const int idx = blockIdx.x * 256 + threadIdx.x;   // 0..262143 = o*512+i
    const float* wp = weight + idx * 9;
    float s = 0.f;
#pragma unroll
    for (int kk = 0; kk < 9; ++kk) {
        float v = wp[kk];
        s += v * v;
        wbf[kk * 262144 + idx] = __float2bfloat16(v);
    }
    wsq[idx] = s * (WEIGHT_GAIN * WEIGHT_GAIN);
}

// ---------------- sc[b][o] = G * rsqrt(sum_i style^2 * wsq + 1e-8) -------------------
__global__ void demod_kernel(const float* __restrict__ style, const float* __restrict__ wsq,
                             float* __restrict__ sc) {
    const int gw = (blockIdx.x * 256 + threadIdx.x) >> 6;  // 0..8191
    const int lane = threadIdx.x & 63;
    const int b = gw >> 9;
    const int o = gw & 511;
    const float4* wq = (const float4*)(wsq + (size_t)o * 512 + lane * 8);
    const float4* st = (const float4*)(style + (size_t)b * 512 + lane * 8);
    float4 q0 = wq[0], q1 = wq[1];
    float4 s0 = st[0], s1 = st[1];
    float acc = q0.x * s0.x * s0.x + q0.y * s0.y * s0.y + q0.z * s0.z * s0.z + q0.w * s0.w * s0.w
              + q1.x * s1.x * s1.x + q1.y * s1.y * s1.y + q1.z * s1.z * s1.z + q1.w * s1.w * s1.w;
#pragma unroll
    for (int off = 32; off > 0; off >>= 1) acc += __shfl_down(acc, off, 64);
    if (lane == 0) sc[(size_t)b * 512 + o] = rsqrtf(acc + 1e-8f) * WEIGHT_GAIN;
}

// ---------------- xs_pad[b][y+1][x+1][i] = bf16(style[b][i] * x[b][i][y][x]) ---------
// blockIdx.x == 64 blocks handle the zero pad ring (fused old border_kernel).
__global__ void xs_kernel(const float* __restrict__ x, const float* __restrict__ style,
                          __hip_bfloat16* __restrict__ xsp) {
    const int b = blockIdx.z;
    const int t = threadIdx.x;
    if (blockIdx.x == 64) {
        // zero the 260-pixel pad ring, 65 pixels per blockIdx.y group
        const int g = blockIdx.y;
        const int wv = t >> 6, lane = t & 63;
        for (int k = wv; k < 65; k += 4) {
            const int p = g * 65 + k;    // 0..259
            int row, col;
            if (p < 66)       { row = 0;            col = p; }
            else if (p < 132) { row = 65;           col = p - 66; }
            else if (p < 196) { row = p - 132 + 1;  col = 0; }
            else              { row = p - 196 + 1;  col = 65; }
            uint4* dst = (uint4*)(xsp + (((size_t)b * PAD_W + row) * PAD_W + col) * XS_PIX_STRIDE);
            dst[lane] = uint4{0, 0, 0, 0};
        }
        return;
    }
    const int y = blockIdx.x;            // image row 0..63
    const int lane = t & 63;             // pixel x
    const int j0 = (blockIdx.y * 4 + (t >> 6)) * 32;   // channel group of 32

    const float* xb = x + (((size_t)b * 512 + j0) * 64 + y) * 64 + lane;
    const float* stb = style + (size_t)b * 512 + j0;
    __hip_bfloat16* dst = xsp + (((size_t)b * PAD_W + (y + 1)) * PAD_W + (lane + 1)) * XS_PIX_STRIDE + j0;

    union { __hip_bfloat16 h[32]; uint4 u[4]; } pk;
#pragma unroll
    for (int k = 0; k < 32; ++k) {
        float v = xb[(size_t)k * 4096];
        pk.h[k] = __float2bfloat16(v * stb[k]);
    }
#pragma unroll
    for (int q = 0; q < 4; ++q) ((uint4*)dst)[q] = pk.u[q];
}

// ---------------- conv: implicit GEMM, M=512(o) x N=4096(p) per batch, K=9*512 -------
// 256x128 tile, BK=64, 8 waves (4M x 2N), 3-deep STATIC LDS ring, distance-2 prefetch
// with counted vmcnt(6) (never drained to 0 in the main loop), raw s_barrier, setprio.
// LDS: 3 x (A 256x64 = 32KB + B 128x64 = 16KB) = 144 KB static (gfx950 allows 160KB/WG).
__global__ __launch_bounds__(512, 1) void conv_kernel(const __hip_bfloat16* __restrict__ wbf,
                            const __hip_bfloat16* __restrict__ xsp,
                            const float* __restrict__ sc,
                            float* __restrict__ out) {
    __shared__ char lds[147456];   // ring r: A at r*49152, B at r*49152 + 32768

    // bijective XCD-aware block id: bits [2:0]=p_lo [3]=m [5:4]=p_hi [9:6]=b
    // -> the two m-tiles sharing a B-panel differ by 8 => same XCD L2.
    const int id = blockIdx.x;
    const int pidx = (id & 7) | (((id >> 4) & 3) << 3);  // 0..31 spatial tile
    const int m0 = ((id >> 3) & 1) << 8;                 // 0 / 256
    const int b  = id >> 6;                              // batch
    const int p0 = pidx << 7;                            // 128 pixels = 2 image rows
    const int y0 = p0 >> 6;
    const int t = threadIdx.x;

    // --- staging thread mapping (XOR-swizzled source k-group, linear LDS dest) ---
    const int r_base = t >> 3;                 // 0..63
    const int s_slot = (t & 7) ^ (r_base & 7);
    const size_t abase = (size_t)(m0 + r_base) * 512 + s_slot * 8;
    int pixoff[2];
#pragma unroll
    for (int q = 0; q < 2; ++q) {
        const int rB = q * 64 + r_base;        // B-tile row 0..127
        const int yy = y0 + (rB >> 6);         // un-shifted padded row (tap adds ky)
        const int xx = rB & 63;
        pixoff[q] = (((b * PAD_W) + yy) * PAD_W + xx) * XS_PIX_STRIDE + s_slot * 8;
    }

    // --- compute thread mapping: 8 waves = 4M x 2N, each wave 64x64 output ---
    const int wv = t >> 6;
    const int wm = (wv >> 1) * 64;
    const int wn = (wv & 1) * 64;
    const int lane = t & 63;
    const int ln15 = lane & 15;
    const int quad = lane >> 4;

    f32x4 acc[4][4] = {};

#define STAGE(S, R) do {                                                              \
    const int kk_ = (S) >> 3;                                                         \
    const int c0_ = ((S) & 7) << 6;                                                   \
    const __hip_bfloat16* wsrc_ = wbf + kk_ * 262144 + abase + c0_;                   \
    char* Ab_ = lds + (R) * 49152;                                                    \
    _Pragma("unroll")                                                                 \
    for (int q = 0; q < 4; ++q)                                                       \
        __builtin_amdgcn_global_load_lds(                                             \
            (const __attribute__((address_space(1))) unsigned int*)(wsrc_ + q * 32768),\
            (__attribute__((address_space(3))) unsigned int*)(Ab_ + q * 8192 + t * 16),\
            16, 0, 0);                                                                \
    const int shift_ = ((kk_ / 3) * PAD_W + (kk_ % 3)) * XS_PIX_STRIDE;               \
    const __hip_bfloat16* xb_ = xsp + shift_ + c0_;                                   \
    char* Bb_ = lds + (R) * 49152 + 32768;                                            \
    _Pragma("unroll")                                                                 \
    for (int q = 0; q < 2; ++q)                                                       \
        __builtin_amdgcn_global_load_lds(                                             \
            (const __attribute__((address_space(1))) unsigned int*)(xb_ + pixoff[q]), \
            (__attribute__((address_space(3))) unsigned int*)(Bb_ + q * 8192 + t * 16),\
            16, 0, 0);                                                                \
} while (0)

#define COMPUTE(R) do {                                                               \
    const short* Ap_ = (const short*)(lds + (R) * 49152);                             \
    const short* Bp_ = (const short*)(lds + (R) * 49152 + 32768);                     \
    _Pragma("unroll")                                                                 \
    for (int ks = 0; ks < 2; ++ks) {                                                  \
        const int gq = ks * 4 + quad;                                                 \
        frag8 af[4], bfr[4];                                                          \
        _Pragma("unroll")                                                             \
        for (int mt = 0; mt < 4; ++mt) {                                              \
            const int R_ = wm + mt * 16 + ln15;                                       \
            af[mt] = *(const frag8*)(Ap_ + R_ * 64 + ((gq ^ (R_ & 7)) << 3));         \
        }                                                                             \
        _Pragma("unroll")                                                             \
        for (int nt = 0; nt < 4; ++nt) {                                              \
            const int R_ = wn + nt * 16 + ln15;                                       \
            bfr[nt] = *(const frag8*)(Bp_ + R_ * 64 + ((gq ^ (R_ & 7)) << 3));        \
        }                                                                             \
        __builtin_amdgcn_s_setprio(1);                                                \
        _Pragma("unroll")                                                             \
        for (int mt = 0; mt < 4; ++mt)                                                \
            _Pragma("unroll")                                                         \
            for (int nt = 0; nt < 4; ++nt)                                            \
                acc[mt][nt] = __builtin_amdgcn_mfma_f32_16x16x32_bf16(                \
                    af[mt], bfr[nt], acc[mt][nt], 0, 0, 0);                           \
        __builtin_amdgcn_s_setprio(0);                                                \
    }                                                                                 \
} while (0)

#define WAIT6 asm volatile("s_waitcnt vmcnt(6)" ::: "memory")
#define BAR   asm volatile("s_barrier" ::: "memory")

// steady-state iteration: wait own 6 loads of step s (12 in flight), collective
// barrier, prefetch step s+2 into ring RS (= ring read at step s-1, safe behind
// two barriers), compute step s from ring RC, barrier before next overwrite.
#define ITER_S(RC, RS) do { WAIT6; BAR; STAGE(s + 2, RS); COMPUTE(RC); BAR; ++s; } while (0)
#define ITER_N(RC)     do { WAIT6; BAR;                   COMPUTE(RC); BAR; ++s; } while (0)

    // 72 K-steps total: s = kk*8 + c0/64
    STAGE(0, 0);
    STAGE(1, 1);
    int s = 0;
    while (s < 69) { ITER_S(0, 2); ITER_S(1, 0); ITER_S(2, 1); }  // 23 passes, s -> 69
    ITER_S(0, 2);   // s = 69, stages step 71 into ring 2
    ITER_N(1);      // s = 70, nothing left to stage
    asm volatile("s_waitcnt vmcnt(0)" ::: "memory");   // drain last step's loads
    BAR;
    COMPUTE(2);     // s = 71

#undef ITER_S
#undef ITER_N
#undef WAIT6
#undef BAR
#undef STAGE
#undef COMPUTE

    // ---- epilogue: scale by G*demod[b][o], store fp32 NCHW ----
    const float* scb = sc + b * 512;
    float* outb = out + (size_t)b * 512 * 4096;
#pragma unroll
    for (int mt = 0; mt < 4; ++mt) {
        const int mrow = m0 + wm + mt * 16 + quad * 4;
#pragma unroll
        for (int v = 0; v < 4; ++v) {
            const float sv = scb[mrow + v];
            float* orow = outb + (size_t)(mrow + v) * 4096 + p0 + wn + ln15;
#pragma unroll
            for (int nt = 0; nt < 4; ++nt)
                orow[nt * 16] = acc[mt][nt][v] * sv;
        }
    }
}

extern "C" void kernel_launch(void* const* d_in, const int* in_sizes, int n_in,
                              void* d_out, int out_size, void* d_ws, size_t ws_size,
                              hipStream_t stream) {
    (void)in_sizes; (void)n_in; (void)out_size; (void)ws_size;
    const float* x      = (const float*)d_in[0];
    const float* w      = (const float*)d_in[1];
    const float* weight = (const float*)d_in[2];
    const float* mw     = (const float*)d_in[3];
    const float* mb     = (const float*)d_in[4];
    float* out = (float*)d_out;

    char* ws = (char*)d_ws;
    float* style         = (float*)(ws + 0);        //  32 KB
    float* sc            = (float*)(ws + 32768);    //  32 KB
    float* wsq           = (float*)(ws + 65536);    //   1 MB
    __hip_bfloat16* wbf  = (__hip_bfloat16*)(ws + 1114112);  // 4.5 MB  [9][512][512]
    __hip_bfloat16* xsp  = (__hip_bfloat16*)(ws + 5832704);  // 68 MB   [16][66][66][512]

    wprep_kernel<<<dim3(1024), dim3(256), 0, stream>>>(weight, wsq, wbf);
    style_kernel<<<dim3(2048), dim3(256), 0, stream>>>(w, mw, mb, style);
    demod_kernel<<<dim3(2048), dim3(256), 0, stream>>>(style, wsq, sc);
    xs_kernel<<<dim3(65, 4, BATCH), dim3(256), 0, stream>>>(x, style, xsp);
    conv_kernel<<<dim3(1024), dim3(512), 0, stream>>>(wbf, xsp, sc, out);
}

// Round 3
// 490.204 us; speedup vs baseline: 1.0974x; 1.0937x over previous
//
#include <hip/hip_runtime.h>
#include <hip/hip_bf16.h>

#define IN_CH 512
#define OUT_CH 512
#define HW 64
#define BATCH 16
#define WEIGHT_GAIN 0.014731391274719739f    // 1/sqrt(512*9)
#define MOD_WEIGHT_GAIN 0.04419417382415922f // 1/sqrt(512)

// padded NHWC xs buffer: [B][66][66][512] bf16
#define PAD_W 66
#define XS_PIX_STRIDE 512

typedef __attribute__((ext_vector_type(8))) short frag8;
typedef __attribute__((ext_vector_type(4))) float f32x4;

// ---------------- style[b][i] = (sum_j w[b][j]*mw[i][j])*g + mb[i] ----------------
__global__ void style_kernel(const float* __restrict__ w, const float* __restrict__ mw,
                             const float* __restrict__ mb, float* __restrict__ style) {
    const int gw = (blockIdx.x * 256 + threadIdx.x) >> 6;  // 0..8191
    const int lane = threadIdx.x & 63;
    const int b = gw >> 9;
    const int i = gw & 511;
    const float4* mwp = (const float4*)(mw + (size_t)i * 512 + lane * 8);
    const float4* wp  = (const float4*)(w + (size_t)b * 512 + lane * 8);
    float4 m0 = mwp[0], m1 = mwp[1];
    float4 w0 = wp[0],  w1 = wp[1];
    float s = m0.x * w0.x + m0.y * w0.y + m0.z * w0.z + m0.w * w0.w
            + m1.x * w1.x + m1.y * w1.y + m1.z * w1.z + m1.w * w1.w;
#pragma unroll
    for (int off = 32; off > 0; off >>= 1) s += __shfl_down(s, off, 64);
    if (lane == 0) style[(size_t)b * 512 + i] = s * MOD_WEIGHT_GAIN + mb[i];
}

// ---------------- wsq[o][i] = G^2 * sum_kk weight^2 ; wbf[kk][o][i] = bf16(weight) ----
__global__ void wprep_kernel(const float* __restrict__ weight, float* __restrict__ wsq,
                             __hip_bfloat16* __restrict__ wbf) {
    const int idx = blockIdx.x * 256 + threadIdx.x;   // 0..262143 = o*512+i
    const float* wp = weight + idx * 9;
    float s = 0.f;
#pragma unroll
    for (int kk = 0; kk < 9; ++kk) {
        float v = wp[kk];
        s += v * v;
        wbf[kk * 262144 + idx] = __float2bfloat16(v);
    }
    wsq[idx] = s * (WEIGHT_GAIN * WEIGHT_GAIN);
}

// ---------------- sc[b][o] = G * rsqrt(sum_i style^2 * wsq + 1e-8) -------------------
__global__ void demod_kernel(const float* __restrict__ style, const float* __restrict__ wsq,
                             float* __restrict__ sc) {
    const int gw = (blockIdx.x * 256 + threadIdx.x) >> 6;  // 0..8191
    const int lane = threadIdx.x & 63;
    const int b = gw >> 9;
    const int o = gw & 511;
    const float4* wq = (const float4*)(wsq + (size_t)o * 512 + lane * 8);
    const float4* st = (const float4*)(style + (size_t)b * 512 + lane * 8);
    float4 q0 = wq[0], q1 = wq[1];
    float4 s0 = st[0], s1 = st[1];
    float acc = q0.x * s0.x * s0.x + q0.y * s0.y * s0.y + q0.z * s0.z * s0.z + q0.w * s0.w * s0.w
              + q1.x * s1.x * s1.x + q1.y * s1.y * s1.y + q1.z * s1.z * s1.z + q1.w * s1.w * s1.w;
#pragma unroll
    for (int off = 32; off > 0; off >>= 1) acc += __shfl_down(acc, off, 64);
    if (lane == 0) sc[(size_t)b * 512 + o] = rsqrtf(acc + 1e-8f) * WEIGHT_GAIN;
}

// ---------------- xs_pad[b][y+1][x+1][i] = bf16(style[b][i] * x[b][i][y][x]) ---------
// blockIdx.x == 64 blocks handle the zero pad ring (fused border kernel).
__global__ void xs_kernel(const float* __restrict__ x, const float* __restrict__ style,
                          __hip_bfloat16* __restrict__ xsp) {
    const int b = blockIdx.z;
    const int t = threadIdx.x;
    if (blockIdx.x == 64) {
        const int g = blockIdx.y;
        const int wv = t >> 6, lane = t & 63;
        for (int k = wv; k < 65; k += 4) {
            const int p = g * 65 + k;    // 0..259
            int row, col;
            if (p < 66)       { row = 0;            col = p; }
            else if (p < 132) { row = 65;           col = p - 66; }
            else if (p < 196) { row = p - 132 + 1;  col = 0; }
            else              { row = p - 196 + 1;  col = 65; }
            uint4* dst = (uint4*)(xsp + (((size_t)b * PAD_W + row) * PAD_W + col) * XS_PIX_STRIDE);
            dst[lane] = uint4{0, 0, 0, 0};
        }
        return;
    }
    const int y = blockIdx.x;            // image row 0..63
    const int lane = t & 63;             // pixel x
    const int j0 = (blockIdx.y * 4 + (t >> 6)) * 32;   // channel group of 32

    const float* xb = x + (((size_t)b * 512 + j0) * 64 + y) * 64 + lane;
    const float* stb = style + (size_t)b * 512 + j0;
    __hip_bfloat16* dst = xsp + (((size_t)b * PAD_W + (y + 1)) * PAD_W + (lane + 1)) * XS_PIX_STRIDE + j0;

    union { __hip_bfloat16 h[32]; uint4 u[4]; } pk;
#pragma unroll
    for (int k = 0; k < 32; ++k) {
        float v = xb[(size_t)k * 4096];
        pk.h[k] = __float2bfloat16(v * stb[k]);
    }
#pragma unroll
    for (int q = 0; q < 4; ++q) ((uint4*)dst)[q] = pk.u[q];
}

// ---------------- conv: implicit GEMM, 8-phase 256x256 template --------------------
// M=512(o) x N=4096(p) per batch, K=9*512. Block tile 256x256, BK=64, 8 waves (2Mx4N),
// wave tile 128x64 (acc[8][4]). LDS 128KB = 2 dbuf x (A 256x64 + B 256x64) bf16,
// staged in 16KB half-tiles (2 x global_load_lds 16B/thread). 4 phases per K-tile:
// {ds_read subtile || stage 1 half -> bar -> lgkm(0) -> setprio1 16xMFMA setprio0 -> bar}
// vmcnt(6) once per K-tile (3 halves in flight, never 0 in main loop).
__global__ __launch_bounds__(512, 1) void conv_kernel(const __hip_bfloat16* __restrict__ wbf,
                            const __hip_bfloat16* __restrict__ xsp,
                            const float* __restrict__ sc,
                            float* __restrict__ out) {
    __shared__ char lds[131072];   // buf c: A [256][64] at c*65536, B [256][64] at +32768

    // XCD chunking: 512 blocks, 64 consecutive logical ids per XCD (bijective, 512%8==0)
    const int bid = blockIdx.x;
    const int logical = (bid & 7) * 64 + (bid >> 3);
    const int m0 = (logical & 1) << 8;        // 0 / 256
    const int pt = (logical >> 1) & 15;       // pixel tile 0..15
    const int b  = logical >> 5;              // batch
    const int p0 = pt << 8;                   // 256 pixels = 4 image rows
    const int y0 = pt << 2;
    const int t = threadIdx.x;

    // --- staging mapping: LDS[row][c] = global[row][c ^ (row&7)] (conflict-free reads) ---
    const int r_base = t >> 3;                 // 0..63
    const int s_slot = (t & 7) ^ (r_base & 7);
    int pixoff[4];
#pragma unroll
    for (int i = 0; i < 4; ++i) {
        const int ri = i * 64 + r_base;        // pixel row in tile 0..255
        const int yy = y0 + (ri >> 6);         // un-shifted padded row (tap adds ky)
        const int xx = ri & 63;
        pixoff[i] = (((b * PAD_W) + yy) * PAD_W + xx) * XS_PIX_STRIDE + s_slot * 8;
    }

    // --- compute mapping: 8 waves 2M x 4N, wave tile 128x64 ---
    const int wv = t >> 6;
    const int wm = (wv >> 2) * 128;
    const int wn = (wv & 3) * 64;
    const int lane = t & 63;
    const int ln15 = lane & 15;
    const int quad = lane >> 4;

    f32x4 acc[8][4] = {};
    frag8 bfr[4][2];     // B-frags, all read at phase 0, live whole K-tile
    frag8 af[4];         // A-frags ks0 (reused ph0/ph1)
    frag8 ag[8];         // A-frags ks1 (read ph2, used ph2+ph3)

#define GLL(SRC, DST) __builtin_amdgcn_global_load_lds(                               \
    (const __attribute__((address_space(1))) unsigned int*)(SRC),                     \
    (__attribute__((address_space(3))) unsigned int*)(DST), 16, 0, 0)

#define STAGE_A(J, HALF) do {                                                         \
    const int jA_ = (J);                                                              \
    const __hip_bfloat16* srcA_ = wbf + (jA_ >> 3) * 262144                           \
        + (size_t)(m0 + (HALF) * 128 + r_base) * 512 + ((jA_ & 7) << 6) + s_slot * 8; \
    char* dstA_ = lds + (jA_ & 1) * 65536 + (HALF) * 16384 + t * 16;                  \
    GLL(srcA_, dstA_);                                                                \
    GLL(srcA_ + 64 * 512, dstA_ + 8192);                                              \
} while (0)

#define STAGE_B(J, HALF) do {                                                         \
    const int jB_ = (J);                                                              \
    const int kkB_ = jB_ >> 3;                                                        \
    const __hip_bfloat16* srcB_ = xsp + ((kkB_ / 3) * PAD_W + (kkB_ % 3)) * XS_PIX_STRIDE \
        + ((jB_ & 7) << 6);                                                           \
    char* dstB_ = lds + (jB_ & 1) * 65536 + 32768 + (HALF) * 16384 + t * 16;          \
    GLL(srcB_ + pixoff[(HALF) * 2 + 0], dstB_);                                       \
    GLL(srcB_ + pixoff[(HALF) * 2 + 1], dstB_ + 8192);                                \
} while (0)

#define RD_B_ALL(CUR) do {                                                            \
    const short* Bp_ = (const short*)(lds + (CUR) * 65536 + 32768);                   \
    _Pragma("unroll")                                                                 \
    for (int nt = 0; nt < 4; ++nt) {                                                  \
        const int R_ = wn + nt * 16 + ln15;                                           \
        _Pragma("unroll")                                                             \
        for (int ks = 0; ks < 2; ++ks)                                                \
            bfr[nt][ks] = *(const frag8*)(Bp_ + R_ * 64 + (((ks * 4 + quad) ^ (R_ & 7)) << 3)); \
    }                                                                                 \
} while (0)

#define RD_A4(CUR, KS, MTH, DST) do {                                                 \
    const short* Ap_ = (const short*)(lds + (CUR) * 65536);                           \
    _Pragma("unroll")                                                                 \
    for (int mt = 0; mt < 4; ++mt) {                                                  \
        const int R_ = wm + ((MTH) * 4 + mt) * 16 + ln15;                             \
        (DST)[mt] = *(const frag8*)(Ap_ + R_ * 64 + ((((KS) * 4 + quad) ^ (R_ & 7)) << 3)); \
    }                                                                                 \
} while (0)

#define MFMA_Q(AF, MTH, KS) do {                                                      \
    __builtin_amdgcn_s_setprio(1);                                                    \
    _Pragma("unroll")                                                                 \
    for (int mt = 0; mt < 4; ++mt)                                                    \
        _Pragma("unroll")                                                             \
        for (int nt = 0; nt < 4; ++nt)                                                \
            acc[(MTH) * 4 + mt][nt] = __builtin_amdgcn_mfma_f32_16x16x32_bf16(        \
                (AF)[mt], bfr[nt][(KS)], acc[(MTH) * 4 + mt][nt], 0, 0, 0);           \
    __builtin_amdgcn_s_setprio(0);                                                    \
} while (0)

#define BAR __builtin_amdgcn_s_barrier()
#define LGKM0 do { asm volatile("s_waitcnt lgkmcnt(0)" ::: "memory");                 \
                   __builtin_amdgcn_sched_barrier(0); } while (0)
#define VM6 asm volatile("s_waitcnt vmcnt(6)" ::: "memory")
#define VM0 asm volatile("s_waitcnt vmcnt(0)" ::: "memory")

// K-tile J in buffer CUR. Stage schedule (steady): ph0: A1(J+1) -> buf(J+1);
// ph1: B0(J+2), ph2: B1(J+2), ph3: A0(J+2) -> buf(J) (regions freed by read schedule:
// B(J) fully read ph0, A(J) fully read ph2). vmcnt at ph3 forces A1(J+1)+older done.
#define KTILE(J, CUR, SP1, SP2, VMC) do {                                             \
    /* phase 0: B all + A mt0-3 ks0 (12 reads) */                                     \
    RD_B_ALL(CUR);                                                                    \
    RD_A4(CUR, 0, 0, af);                                                             \
    if (SP1) STAGE_A((J) + 1, 1);                                                     \
    BAR; LGKM0; MFMA_Q(af, 0, 0); BAR;                                                \
    /* phase 1: A mt4-7 ks0 (4 reads) */                                              \
    RD_A4(CUR, 0, 1, af);                                                             \
    if (SP2) STAGE_B((J) + 2, 0);                                                     \
    BAR; LGKM0; MFMA_Q(af, 1, 0); BAR;                                                \
    /* phase 2: A mt0-7 ks1 (8 reads) */                                              \
    RD_A4(CUR, 1, 0, ag);                                                             \
    RD_A4(CUR, 1, 1, ag + 4);                                                         \
    if (SP2) STAGE_B((J) + 2, 1);                                                     \
    BAR; LGKM0; MFMA_Q(ag, 0, 1); BAR;                                                \
    /* phase 3: no reads */                                                           \
    if (SP2) STAGE_A((J) + 2, 0);                                                     \
    VMC; BAR; MFMA_Q(ag + 4, 1, 1); BAR;                                              \
} while (0)

    // prologue: 7 halves (K-tile 0 complete + K-tile 1 minus A1); vmcnt(6) forces k0 done
    STAGE_B(0, 0); STAGE_B(0, 1); STAGE_A(0, 0); STAGE_A(0, 1);
    STAGE_B(1, 0); STAGE_B(1, 1); STAGE_A(1, 0);
    VM6; BAR;

    for (int j = 0; j < 70; j += 2) {
        KTILE(j, 0, 1, 1, VM6);
        KTILE(j + 1, 1, 1, 1, VM6);
    }
    KTILE(70, 0, 1, 0, VM0);       // stages only A1(71); drain to it
    KTILE(71, 1, 0, 0, (void)0);   // pure compute

#undef KTILE
#undef VM0
#undef VM6
#undef LGKM0
#undef BAR
#undef MFMA_Q
#undef RD_A4
#undef RD_B_ALL
#undef STAGE_B
#undef STAGE_A
#undef GLL

    // ---- epilogue: scale by G*demod[b][o], store fp32 NCHW ----
    const float* scb = sc + b * 512;
    float* outb = out + (size_t)b * 512 * 4096;
#pragma unroll
    for (int mt = 0; mt < 8; ++mt) {
        const int mrow = m0 + wm + mt * 16 + quad * 4;
#pragma unroll
        for (int v = 0; v < 4; ++v) {
            const float sv = scb[mrow + v];
            float* orow = outb + (size_t)(mrow + v) * 4096 + p0 + wn + ln15;
#pragma unroll
            for (int nt = 0; nt < 4; ++nt)
                orow[nt * 16] = acc[mt][nt][v] * sv;
        }
    }
}

extern "C" void kernel_launch(void* const* d_in, const int* in_sizes, int n_in,
                              void* d_out, int out_size, void* d_ws, size_t ws_size,
                              hipStream_t stream) {
    (void)in_sizes; (void)n_in; (void)out_size; (void)ws_size;
    const float* x      = (const float*)d_in[0];
    const float* w      = (const float*)d_in[1];
    const float* weight = (const float*)d_in[2];
    const float* mw     = (const float*)d_in[3];
    const float* mb     = (const float*)d_in[4];
    float* out = (float*)d_out;

    char* ws = (char*)d_ws;
    float* style         = (float*)(ws + 0);        //  32 KB
    float* sc            = (float*)(ws + 32768);    //  32 KB
    float* wsq           = (float*)(ws + 65536);    //   1 MB
    __hip_bfloat16* wbf  = (__hip_bfloat16*)(ws + 1114112);  // 4.5 MB  [9][512][512]
    __hip_bfloat16* xsp  = (__hip_bfloat16*)(ws + 5832704);  // 68 MB   [16][66][66][512]

    wprep_kernel<<<dim3(1024), dim3(256), 0, stream>>>(weight, wsq, wbf);
    style_kernel<<<dim3(2048), dim3(256), 0, stream>>>(w, mw, mb, style);
    demod_kernel<<<dim3(2048), dim3(256), 0, stream>>>(style, wsq, sc);
    xs_kernel<<<dim3(65, 4, BATCH), dim3(256), 0, stream>>>(x, style, xsp);
    conv_kernel<<<dim3(512), dim3(512), 0, stream>>>(wbf, xsp, sc, out);
}